// Round 16
// baseline (58.468 us; speedup 1.0000x reference)
//
#include <hip/hip_runtime.h>
#include <cfloat>

// ---------------------------------------------------------------------------
// VQ-VAE vector quantizer forward (MI355X / gfx950)
//   x        [32][64][64][64] f32   (B, D, H, W)
//   codebook [1024][64] f32
// out: x_q transposed back to [B,D,H,W] (8388608 f32)  +  loss scalar (1 f32)
//
// argmin_k ||x - c_k||^2  ==  argmax_k (x . c_k - ||c_k||^2/2)
// Sum_p SSE_p = Sum x^2 - 2 * Sum_p (best_score_p - 1),
//   score = dot + 1 - ||c||^2/2 (C-init), packed-u32 argmax (R5/R9-proven).
//
// R16 = R13's exact inner loop, restructured to cut block turnover (the one
// signal tracking the 40us plateau: ~2.6 blocks/CU resident regardless of
// allowance) and fixed overhead:
//  (1) 2 rows per block sequential (1024 blocks): one prologue/epilogue per
//      2 rows; row-1 x loads issued during row-0's merge/output (T14).
//  (2) loss fused into vq_main via one atomicAdd/block on the out scalar
//      (vq_pre zeroes it each call) -> vq_loss kernel + partials deleted.
// Canaries: VGPR<=76, FETCH~18.5MB, WRITE~32.8MB, conflicts~260K.
// ---------------------------------------------------------------------------

#define DD    64
#define HHWW  4096         // H*W
#define KC    1024
#define NBLKM 1024         // one block per 2 rows
#define NPOSD 8388608.0f   // N * D

typedef __bf16  bf16x8 __attribute__((ext_vector_type(8)));
typedef float   f32x4  __attribute__((ext_vector_type(4)));

__device__ __forceinline__ unsigned short bf16_bits(float f) {
  unsigned u = __float_as_uint(f);
  return (unsigned short)((u + 0x7FFFu + ((u >> 16) & 1u)) >> 16);  // RNE
}

__device__ __forceinline__ unsigned int umax2(unsigned int a, unsigned int b) {
  return a > b ? a : b;
}

// --- precompute: fragment-ordered bf16 codebook + replicated (1-||c||^2/2) --
// thread = (code k, dim-quad q); coalesced float4 read, 16-lane shfl reduce.
// Block 0 also zeroes the fused-loss accumulator (runs before vq_main).
__global__ __launch_bounds__(256) void vq_pre(
    const float* __restrict__ cb,          // [1024][64]
    unsigned short* __restrict__ cb_frag,  // [tile=64][kk=2][lane=64][e=8]
    float* __restrict__ hneg4,             // [1024][4] : 1-||c||^2/2, x4
    float* __restrict__ loss_out)
{
  if (blockIdx.x == 0 && threadIdx.x == 0) loss_out[0] = 0.f;

  const int gt = blockIdx.x * 256 + threadIdx.x;  // 0..16383
  const int k  = gt >> 4;                          // code 0..1023
  const int q  = gt & 15;                          // dim quad 0..15
  const float4 v = *(const float4*)(cb + (size_t)k * DD + q * 4);

  float s = v.x * v.x + v.y * v.y + v.z * v.z + v.w * v.w;
#pragma unroll
  for (int m = 1; m < 16; m <<= 1) s += __shfl_xor(s, m, 64);  // 16-group sum
  if (q == 0) {
    const float mval = 1.0f - 0.5f * s;
    float4 m4; m4.x = mval; m4.y = mval; m4.z = mval; m4.w = mval;
    *(float4*)(hneg4 + (size_t)k * 4) = m4;
  }

  const int d0 = q * 4;
  const int kk = d0 >> 5, g = (d0 >> 3) & 3, e0 = d0 & 7;
  const int t = k >> 4, l15 = k & 15;
  unsigned short u0 = bf16_bits(v.x), u1 = bf16_bits(v.y);
  unsigned short u2 = bf16_bits(v.z), u3 = bf16_bits(v.w);
  uint2 wv2;
  wv2.x = (unsigned int)u0 | ((unsigned int)u1 << 16);
  wv2.y = (unsigned int)u2 | ((unsigned int)u3 << 16);
  *(uint2*)(&cb_frag[(((t * 2 + kk) * 64) + (g * 16 + l15)) * 8 + e0]) = wv2;
}

// --- main: fused distance-GEMM + argmin + loss + output, 2 rows/block ------
__global__ __launch_bounds__(256) void vq_main(
    const float* __restrict__ x,
    const unsigned short* __restrict__ cb_frag,
    const float* __restrict__ hneg4,
    const float* __restrict__ cb,
    float* __restrict__ out,
    float* __restrict__ loss_out)
{
  __shared__ unsigned short xfrag[4096];   //  8 KB: current row A-fragments
  __shared__ unsigned int   cand[4][64];   //  1 KB: per-wave winners
  __shared__ int            idx_lds[64];
  __shared__ float          xred[4];

  const int tid  = threadIdx.x;
  const int wv   = tid >> 6;
  const int lane = tid & 63;
  const int l15  = lane & 15;
  const int g    = lane >> 4;

  // XCD-aware swizzle over 1024 row-pairs (bijective): XCD n owns a
  // contiguous 256-row slab.
  const int pair = ((blockIdx.x & 7) << 7) + (blockIdx.x >> 3);  // 0..1023
  const int row0 = pair * 2;
  const int b    = row0 >> 6;
  const int h0   = row0 & 63;
  const float* xb = x + (size_t)b * DD * HHWW + h0 * 64;  // xb[d*4096 + w]

  // per-thread staging coordinates (constant across rows)
  // float4 #m covers (d = m>>4, w = (m&15)*4 .. +3); 256B segments.
  const int m0 = tid, m1 = tid + 256, m2 = tid + 512, m3 = tid + 768;
  const int dA = m0 >> 4, dB = m1 >> 4, dC = m2 >> 4, dE = m3 >> 4;
  const int wA = m0 & 15, wB = m1 & 15, wC = m2 & 15, wE = m3 & 15;

  // wave-constant B/mh pointers (K-split: codes wv*256 .. +255)
  const unsigned int MASK = 0xFFFFFC00u;
  const int codec0 = 1023 - wv * 256 - l15;
  const char*  bb  = (const char*)cb_frag + (size_t)wv * 16 * 2048 + (size_t)lane * 16;
  const f32x4* mhp = (const f32x4*)hneg4 + wv * 256 + l15;   // + t*16 per tile

  float xacc = 0.f;        // Sum x^2 (all threads, both rows)
  float vtacc = 0.f;       // Sum (vt-1) (wave-0 lanes, both rows)

  // preload row 0's x slice
  float4 px0 = *(const float4*)(xb + (size_t)dA * HHWW + wA * 4);
  float4 px1 = *(const float4*)(xb + (size_t)dB * HHWW + wB * 4);
  float4 px2 = *(const float4*)(xb + (size_t)dC * HHWW + wC * 4);
  float4 px3 = *(const float4*)(xb + (size_t)dE * HHWW + wE * 4);

#pragma unroll
  for (int r = 0; r < 2; ++r) {
    // ---- pack px -> xfrag (XOR-swizzled, R12-proven); accumulate x^2 ----
    {
      const float4 pv[4] = {px0, px1, px2, px3};
      const int md[4] = {dA, dB, dC, dE};
      const int mw[4] = {wA, wB, wC, wE};
#pragma unroll
      for (int r4 = 0; r4 < 4; ++r4) {
        const float4 v4 = pv[r4];
        const int d = md[r4], w4 = mw[r4];
        const int kk = d >> 5, gg = (d >> 3) & 3, e = d & 7;
        const int pt = w4 >> 2;
        const int base = pt * 1024 + kk * 512 + gg * 128 + e;
        const int lb = (w4 & 3) * 4;
        xacc += v4.x * v4.x + v4.y * v4.y + v4.z * v4.z + v4.w * v4.w;
        xfrag[base + ((lb + 0) ^ pt) * 8] = bf16_bits(v4.x);
        xfrag[base + ((lb + 1) ^ pt) * 8] = bf16_bits(v4.y);
        xfrag[base + ((lb + 2) ^ pt) * 8] = bf16_bits(v4.z);
        xfrag[base + ((lb + 3) ^ pt) * 8] = bf16_bits(v4.w);
      }
    }
    __syncthreads();                     // A: xfrag(r) ready

    // ---- A fragments (b128, XOR-matched -> conflict-free) ----
    bf16x8 afrag[4][2];
#pragma unroll
    for (int pt = 0; pt < 4; ++pt) {
      const int ls = g * 16 + (l15 ^ pt);
      afrag[pt][0] = *(const bf16x8*)(&xfrag[pt * 1024 + ls * 8]);
      afrag[pt][1] = *(const bf16x8*)(&xfrag[pt * 1024 + 512 + ls * 8]);
    }

    // ---- 16 code tiles, depth-1 prefetch, packed-u32 argmax ----
    unsigned int best[4][4];
#pragma unroll
    for (int pt = 0; pt < 4; ++pt)
#pragma unroll
      for (int rr = 0; rr < 4; ++rr) best[pt][rr] = 0u;

    bf16x8 nb0 = *(const bf16x8*)(bb);          // kk=0
    bf16x8 nb1 = *(const bf16x8*)(bb + 1024);   // kk=1
    f32x4  nmh = mhp[0];

#pragma unroll 4
    for (int t = 0; t < 16; ++t) {
      const bf16x8 b0 = nb0, b1 = nb1;
      const f32x4  mh = nmh;
      const int tn = (t + 1) & 15;
      nb0 = *(const bf16x8*)(bb + tn * 2048);
      nb1 = *(const bf16x8*)(bb + tn * 2048 + 1024);
      nmh = mhp[tn * 16];

      const unsigned int codec = (unsigned int)(codec0 - t * 16);

      f32x4 acc[4];
#pragma unroll
      for (int pt = 0; pt < 4; ++pt)    // C-init = mh4 (no movs)
        acc[pt] = __builtin_amdgcn_mfma_f32_16x16x32_bf16(afrag[pt][0], b0, mh, 0, 0, 0);
#pragma unroll
      for (int pt = 0; pt < 4; ++pt)
        acc[pt] = __builtin_amdgcn_mfma_f32_16x16x32_bf16(afrag[pt][1], b1, acc[pt], 0, 0, 0);

#pragma unroll
      for (int pt = 0; pt < 4; ++pt)
#pragma unroll
        for (int rr = 0; rr < 4; ++rr) {  // C/D: col=l15(code), row=g*4+rr
          const unsigned int p = (__float_as_uint(acc[pt][rr]) & MASK) | codec;
          best[pt][rr] = umax2(best[pt][rr], p);
        }
    }

    // ---- cross-lane max over the 16 code columns (l15) ----
#pragma unroll
    for (int pt = 0; pt < 4; ++pt)
#pragma unroll
      for (int rr = 0; rr < 4; ++rr) {
        unsigned int v = best[pt][rr];
#pragma unroll
        for (int m = 1; m < 16; m <<= 1) {
          unsigned int vo = __shfl_xor(v, m, 64);
          v = umax2(v, vo);
        }
        if (l15 == 0) cand[wv][pt * 16 + g * 4 + rr] = v;
      }
    __syncthreads();                     // B: cand ready

    // ---- wave 0: merge the 4 K-split candidates; vt accumulate ----
    if (tid < 64) {
      unsigned int v01 = umax2(cand[0][tid], cand[1][tid]);
      unsigned int v23 = umax2(cand[2][tid], cand[3][tid]);
      unsigned int v   = umax2(v01, v23);
      idx_lds[tid] = 1023 - (int)(v & 1023u);
      vtacc += __uint_as_float(v & MASK) - 1.0f;   // dot - csq/2 (trunc)
    }

    // ---- issue next row's x loads (land under output+pack, T14) ----
    if (r == 0) {
      px0 = *(const float4*)(xb + (size_t)dA * HHWW + 64 + wA * 4);
      px1 = *(const float4*)(xb + (size_t)dB * HHWW + 64 + wB * 4);
      px2 = *(const float4*)(xb + (size_t)dC * HHWW + 64 + wC * 4);
      px3 = *(const float4*)(xb + (size_t)dE * HHWW + 64 + wE * 4);
    }
    __syncthreads();                     // C: idx_lds ready

    // ---- write quantized output row r; float4 gather from cb ----
    const int myidx = idx_lds[lane];     // position w = lane
    const float4* crow = (const float4*)(cb + (size_t)myidx * DD) + wv * 4;
    const float4 c0 = crow[0], c1 = crow[1], c2 = crow[2], c3 = crow[3];
    float* ob = out + (size_t)b * DD * HHWW + (h0 + r) * 64 + lane;
    ob[(size_t)(wv * 16 +  0) * HHWW] = c0.x;
    ob[(size_t)(wv * 16 +  1) * HHWW] = c0.y;
    ob[(size_t)(wv * 16 +  2) * HHWW] = c0.z;
    ob[(size_t)(wv * 16 +  3) * HHWW] = c0.w;
    ob[(size_t)(wv * 16 +  4) * HHWW] = c1.x;
    ob[(size_t)(wv * 16 +  5) * HHWW] = c1.y;
    ob[(size_t)(wv * 16 +  6) * HHWW] = c1.z;
    ob[(size_t)(wv * 16 +  7) * HHWW] = c1.w;
    ob[(size_t)(wv * 16 +  8) * HHWW] = c2.x;
    ob[(size_t)(wv * 16 +  9) * HHWW] = c2.y;
    ob[(size_t)(wv * 16 + 10) * HHWW] = c2.z;
    ob[(size_t)(wv * 16 + 11) * HHWW] = c2.w;
    ob[(size_t)(wv * 16 + 12) * HHWW] = c3.x;
    ob[(size_t)(wv * 16 + 13) * HHWW] = c3.y;
    ob[(size_t)(wv * 16 + 14) * HHWW] = c3.z;
    ob[(size_t)(wv * 16 + 15) * HHWW] = c3.w;
  }

  // ---- fused loss: block SSE -> one atomicAdd ----
#pragma unroll
  for (int m = 1; m < 64; m <<= 1) xacc += __shfl_xor(xacc, m, 64);
  if (lane == 0) xred[wv] = xacc;
  if (wv == 0) {
#pragma unroll
    for (int m = 1; m < 64; m <<= 1) vtacc += __shfl_xor(vtacc, m, 64);
  }
  __syncthreads();
  if (tid == 0) {
    const float sse = (xred[0] + xred[1] + xred[2] + xred[3]) - 2.0f * vtacc;
    atomicAdd(loss_out, sse * (1.25f / NPOSD));
  }
}

extern "C" void kernel_launch(void* const* d_in, const int* in_sizes, int n_in,
                              void* d_out, int out_size, void* d_ws, size_t ws_size,
                              hipStream_t stream) {
  const float* x  = (const float*)d_in[0];
  const float* cb = (const float*)d_in[1];
  float* out      = (float*)d_out;
  float* loss_out = out + 8388608;

  char* ws = (char*)d_ws;
  unsigned short* cb_frag = (unsigned short*)(ws);      // 131072 B
  float* hneg4    = (float*)(ws + 131072);              //  16384 B

  vq_pre <<<64,    256, 0, stream>>>(cb, cb_frag, hneg4, loss_out);
  vq_main<<<NBLKM, 256, 0, stream>>>(x, cb_frag, hneg4, cb, out, loss_out);
}

// Round 17
// 57.792 us; speedup vs baseline: 1.0117x; 1.0117x over previous
//
#include <hip/hip_runtime.h>
#include <cfloat>

// ---------------------------------------------------------------------------
// VQ-VAE vector quantizer forward (MI355X / gfx950)
//   x        [32][64][64][64] f32   (B, D, H, W)
//   codebook [1024][64] f32
// out: x_q transposed back to [B,D,H,W] (8388608 f32)  +  loss scalar (1 f32)
//
// argmin_k ||x - c_k||^2  ==  argmax_k (x . c_k - ||c_k||^2/2)
// Sum_p SSE_p = Sum x^2 - 2 * Sum_p (best_score_p - 1),
//   score = dot + 1 - ||c||^2/2 (C-init), packed-u32 argmax (R5/R9-proven).
//
// R17: grid-granularity experiment. R16 coarsened 2048->1024 blocks and lost
// 14 us; R17 refines 2048->4096 blocks x 128 thr (2 waves). Block =
// (row, pos-half): stage 32-position half-row (8 KB), wave w scans codes
// w*512..+511 (32 tiles; R13's exact depth-1 loop body with 2 pos-tiles),
// 2-candidate merge, half-row output. Total waves unchanged (8192);
// workgroup granularity halved. B L2 traffic 2x (536 MB ~ 15us aggregate,
// under the 40us plateau) -- accepted for the experiment.
// Canaries: VGPR<=64, FETCH~19MB, WRITE~33MB, conflicts<500K.
// ---------------------------------------------------------------------------

#define DD    64
#define HHWW  4096         // H*W
#define KC    1024
#define NBLKM 4096         // one block per (row, pos-half)
#define NPOSD 8388608.0f   // N * D

typedef __bf16  bf16x8 __attribute__((ext_vector_type(8)));
typedef float   f32x4  __attribute__((ext_vector_type(4)));

__device__ __forceinline__ unsigned short bf16_bits(float f) {
  unsigned u = __float_as_uint(f);
  return (unsigned short)((u + 0x7FFFu + ((u >> 16) & 1u)) >> 16);  // RNE
}

__device__ __forceinline__ unsigned int umax2(unsigned int a, unsigned int b) {
  return a > b ? a : b;
}

// --- precompute: fragment-ordered bf16 codebook + replicated (1-||c||^2/2) --
// thread = (code k, dim-quad q); coalesced float4 read, 16-lane shfl reduce.
__global__ __launch_bounds__(256) void vq_pre(
    const float* __restrict__ cb,          // [1024][64]
    unsigned short* __restrict__ cb_frag,  // [tile=64][kk=2][lane=64][e=8]
    float* __restrict__ hneg4)             // [1024][4] : 1-||c||^2/2, x4
{
  const int gt = blockIdx.x * 256 + threadIdx.x;  // 0..16383
  const int k  = gt >> 4;                          // code 0..1023
  const int q  = gt & 15;                          // dim quad 0..15
  const float4 v = *(const float4*)(cb + (size_t)k * DD + q * 4);

  float s = v.x * v.x + v.y * v.y + v.z * v.z + v.w * v.w;
#pragma unroll
  for (int m = 1; m < 16; m <<= 1) s += __shfl_xor(s, m, 64);  // 16-group sum
  if (q == 0) {
    const float mval = 1.0f - 0.5f * s;
    float4 m4; m4.x = mval; m4.y = mval; m4.z = mval; m4.w = mval;
    *(float4*)(hneg4 + (size_t)k * 4) = m4;
  }

  const int d0 = q * 4;
  const int kk = d0 >> 5, g = (d0 >> 3) & 3, e0 = d0 & 7;
  const int t = k >> 4, l15 = k & 15;
  unsigned short u0 = bf16_bits(v.x), u1 = bf16_bits(v.y);
  unsigned short u2 = bf16_bits(v.z), u3 = bf16_bits(v.w);
  uint2 wv2;
  wv2.x = (unsigned int)u0 | ((unsigned int)u1 << 16);
  wv2.y = (unsigned int)u2 | ((unsigned int)u3 << 16);
  *(uint2*)(&cb_frag[(((t * 2 + kk) * 64) + (g * 16 + l15)) * 8 + e0]) = wv2;
}

// --- main: fused distance-GEMM + argmin + loss partial + output write ------
// 128 threads (2 waves). Block = (row, pos-half ph): 32 positions.
__global__ __launch_bounds__(128) void vq_main(
    const float* __restrict__ x,
    const unsigned short* __restrict__ cb_frag,
    const float* __restrict__ hneg4,
    const float* __restrict__ cb,
    float* __restrict__ out,
    float* __restrict__ partials)
{
  __shared__ unsigned short xfrag[2048];   //  4 KB: half-row A-fragments
  __shared__ unsigned int   cand[2][32];   // per-wave winners (32 positions)
  __shared__ int            idx_lds[32];
  __shared__ float          xred[2];

  const int tid  = threadIdx.x;
  const int wv   = tid >> 6;               // 0..1 (code half)
  const int lane = tid & 63;
  const int l15  = lane & 15;
  const int g    = lane >> 4;

  // XCD-aware bijective swizzle over 4096 blocks (4096 = 8 * 512)
  const int sb  = ((blockIdx.x & 7) << 9) + (blockIdx.x >> 3);
  const int row = sb >> 1;                 // 0..2047
  const int ph  = sb & 1;                  // pos half: positions ph*32..+31
  const int b   = row >> 6;
  const int h   = row & 63;
  const float* xb = x + (size_t)b * DD * HHWW + h * 64 + ph * 32;

  // ---- cooperative coalesced x-stage (32 pos x 64 dims = 8 KB) ----
  // float4 #m covers (d = m>>3, local pos lp = (m&7)*4 .. +3); 128B segs.
  // XOR-swizzle slot (l15 ^ pt') on write AND read (R12-proven).
  float xacc = 0.f;
#pragma unroll
  for (int r4 = 0; r4 < 4; ++r4) {
    const int m  = tid + r4 * 128;         // 0..511
    const int d  = m >> 3;
    const int w8 = m & 7;
    const float4 v4 = *(const float4*)(xb + (size_t)d * HHWW + w8 * 4);
    const int kk = d >> 5, gg = (d >> 3) & 3, e = d & 7;
    const int lp0 = w8 * 4;                // local pos of v4.x
    const int pt = lp0 >> 4;               // local pos-tile (0..1)
    const int base = pt * 1024 + kk * 512 + gg * 128 + e;  // + (l15^pt)*8
    const int lb = lp0 & 15;
    xacc += v4.x * v4.x + v4.y * v4.y + v4.z * v4.z + v4.w * v4.w;
    xfrag[base + ((lb + 0) ^ pt) * 8] = bf16_bits(v4.x);
    xfrag[base + ((lb + 1) ^ pt) * 8] = bf16_bits(v4.y);
    xfrag[base + ((lb + 2) ^ pt) * 8] = bf16_bits(v4.z);
    xfrag[base + ((lb + 3) ^ pt) * 8] = bf16_bits(v4.w);
  }

  __syncthreads();                       // xfrag ready

  // ---- A fragments: 2 local pos-tiles (b128, XOR-matched) ----
  bf16x8 afrag[2][2];
#pragma unroll
  for (int pt = 0; pt < 2; ++pt) {
    const int ls = g * 16 + (l15 ^ pt);
    afrag[pt][0] = *(const bf16x8*)(&xfrag[pt * 1024 + ls * 8]);
    afrag[pt][1] = *(const bf16x8*)(&xfrag[pt * 1024 + 512 + ls * 8]);
  }

  // ---- this wave's 32 code tiles (codes wv*512 .. +511), depth-1 pf ----
  unsigned int best[2][4];
#pragma unroll
  for (int pt = 0; pt < 2; ++pt)
#pragma unroll
    for (int rr = 0; rr < 4; ++rr) best[pt][rr] = 0u;

  const unsigned int MASK = 0xFFFFFC00u;
  const int codec0 = 1023 - wv * 512 - l15;
  const char*  bb  = (const char*)cb_frag + (size_t)wv * 32 * 2048 + (size_t)lane * 16;
  const f32x4* mhp = (const f32x4*)hneg4 + wv * 512 + l15;   // + t*16 per tile

  bf16x8 nb0 = *(const bf16x8*)(bb);          // depth-1 prefetch (kk=0)
  bf16x8 nb1 = *(const bf16x8*)(bb + 1024);   // kk=1
  f32x4  nmh = mhp[0];

#pragma unroll 4
  for (int t = 0; t < 32; ++t) {
    const bf16x8 b0 = nb0, b1 = nb1;
    const f32x4  mh = nmh;
    const int tn = (t + 1) & 31;
    nb0 = *(const bf16x8*)(bb + tn * 2048);
    nb1 = *(const bf16x8*)(bb + tn * 2048 + 1024);
    nmh = mhp[tn * 16];

    const unsigned int codec = (unsigned int)(codec0 - t * 16);

    f32x4 acc[2];
#pragma unroll
    for (int pt = 0; pt < 2; ++pt)      // C-init = mh4 (no movs)
      acc[pt] = __builtin_amdgcn_mfma_f32_16x16x32_bf16(afrag[pt][0], b0, mh, 0, 0, 0);
#pragma unroll
    for (int pt = 0; pt < 2; ++pt)
      acc[pt] = __builtin_amdgcn_mfma_f32_16x16x32_bf16(afrag[pt][1], b1, acc[pt], 0, 0, 0);

#pragma unroll
    for (int pt = 0; pt < 2; ++pt)
#pragma unroll
      for (int rr = 0; rr < 4; ++rr) {  // C/D: col=l15(code), row=g*4+rr(pos)
        const unsigned int p = (__float_as_uint(acc[pt][rr]) & MASK) | codec;
        best[pt][rr] = umax2(best[pt][rr], p);   // v_and_or + v_max
      }
  }

  // ---- cross-lane max over the 16 code columns (l15) ----
#pragma unroll
  for (int pt = 0; pt < 2; ++pt)
#pragma unroll
    for (int rr = 0; rr < 4; ++rr) {
      unsigned int v = best[pt][rr];
#pragma unroll
      for (int m = 1; m < 16; m <<= 1) {
        unsigned int vo = __shfl_xor(v, m, 64);
        v = umax2(v, vo);
      }
      if (l15 == 0) cand[wv][pt * 16 + g * 4 + rr] = v;
    }

  // per-wave Sum x^2 reduce
#pragma unroll
  for (int m = 1; m < 64; m <<= 1) xacc += __shfl_xor(xacc, m, 64);
  if (lane == 0) xred[wv] = xacc;

  __syncthreads();

  // ---- merge the 2 code-half candidates (tid<32); loss partial ----
  if (tid < 32) {
    const unsigned int v = umax2(cand[0][tid], cand[1][tid]);
    idx_lds[tid] = 1023 - (int)(v & 1023u);
    float vt1 = __uint_as_float(v & MASK) - 1.0f;   // dot - csq/2 (trunc)
#pragma unroll
    for (int m = 1; m < 32; m <<= 1) vt1 += __shfl_xor(vt1, m, 64);
    if (tid == 0)
      partials[blockIdx.x] = (xred[0] + xred[1]) - 2.0f * vt1;
  }

  __syncthreads();

  // ---- write quantized output; float4 gather from row-major cb ----
  // thread = (lp = tid&31, dchunk = tid>>5): 16 d-rows each, 128B segments.
  const int lp = tid & 31;
  const int dc = tid >> 5;                 // 0..3
  const int myidx = idx_lds[lp];
  const float4* crow = (const float4*)(cb + (size_t)myidx * DD) + dc * 4;
  const float4 c0 = crow[0], c1 = crow[1], c2 = crow[2], c3 = crow[3];
  float* ob = out + (size_t)b * DD * HHWW + h * 64 + ph * 32 + lp;
  ob[(size_t)(dc * 16 +  0) * HHWW] = c0.x;
  ob[(size_t)(dc * 16 +  1) * HHWW] = c0.y;
  ob[(size_t)(dc * 16 +  2) * HHWW] = c0.z;
  ob[(size_t)(dc * 16 +  3) * HHWW] = c0.w;
  ob[(size_t)(dc * 16 +  4) * HHWW] = c1.x;
  ob[(size_t)(dc * 16 +  5) * HHWW] = c1.y;
  ob[(size_t)(dc * 16 +  6) * HHWW] = c1.z;
  ob[(size_t)(dc * 16 +  7) * HHWW] = c1.w;
  ob[(size_t)(dc * 16 +  8) * HHWW] = c2.x;
  ob[(size_t)(dc * 16 +  9) * HHWW] = c2.y;
  ob[(size_t)(dc * 16 + 10) * HHWW] = c2.z;
  ob[(size_t)(dc * 16 + 11) * HHWW] = c2.w;
  ob[(size_t)(dc * 16 + 12) * HHWW] = c3.x;
  ob[(size_t)(dc * 16 + 13) * HHWW] = c3.y;
  ob[(size_t)(dc * 16 + 14) * HHWW] = c3.z;
  ob[(size_t)(dc * 16 + 15) * HHWW] = c3.w;
}

// --- final loss reduce ------------------------------------------------------
__global__ __launch_bounds__(256) void vq_loss(
    const float* __restrict__ partials, float* __restrict__ loss_out)
{
  __shared__ float sred[4];
  int tid = threadIdx.x;
  float s = 0.f;
  for (int i = tid; i < NBLKM; i += 256) s += partials[i];
#pragma unroll
  for (int m = 1; m < 64; m <<= 1) s += __shfl_xor(s, m, 64);
  if ((tid & 63) == 0) sred[tid >> 6] = s;
  __syncthreads();
  if (tid == 0)
    loss_out[0] = (sred[0] + sred[1] + sred[2] + sred[3]) * (1.25f / NPOSD);
}

extern "C" void kernel_launch(void* const* d_in, const int* in_sizes, int n_in,
                              void* d_out, int out_size, void* d_ws, size_t ws_size,
                              hipStream_t stream) {
  const float* x  = (const float*)d_in[0];
  const float* cb = (const float*)d_in[1];
  float* out      = (float*)d_out;
  float* loss_out = out + 8388608;

  char* ws = (char*)d_ws;
  unsigned short* cb_frag = (unsigned short*)(ws);      // 131072 B
  float* hneg4    = (float*)(ws + 131072);              //  16384 B
  float* partials = (float*)(ws + 147456);              //  16384 B

  vq_pre <<<64,    256, 0, stream>>>(cb, cb_frag, hneg4);
  vq_main<<<NBLKM, 128, 0, stream>>>(x, cb_frag, hneg4, cb, out, partials);
  vq_loss<<<1,     256, 0, stream>>>(partials, loss_out);
}